// Round 10
// baseline (319.252 us; speedup 1.0000x reference)
//
#include <hip/hip_runtime.h>
#include <hip/hip_bf16.h>
#include <hip/hip_fp16.h>
#include <math.h>

#define HID 64

#if defined(__has_builtin)
#if __has_builtin(__builtin_amdgcn_cvt_pk_f32_fp8) && __has_builtin(__builtin_amdgcn_cvt_pk_fp8_f32)
#define HWFP8 1
#endif
#endif

typedef float vfloat2 __attribute__((ext_vector_type(2)));
typedef __attribute__((ext_vector_type(8))) short short8_t;   // 8 bf16 (4 VGPRs)
typedef __attribute__((ext_vector_type(4))) float f32x4;

union ABFrag { short8_t s; unsigned short u[8]; };

// ---------------- helpers ----------------

__device__ __forceinline__ unsigned short f2bf(float x) {
    unsigned int u = __float_as_uint(x);
    unsigned int r = u + 0x7fffu + ((u >> 16) & 1u);   // RNE
    return (unsigned short)(r >> 16);
}

#ifndef HWFP8
__device__ __forceinline__ unsigned int enc8_sw(float a) {
    unsigned short hb = __half_as_ushort(__float2half(a));
    unsigned int r = (unsigned int)hb + 0x7fu + ((hb >> 8) & 1u);
    return (r >> 8) & 0xffu;
}
__device__ __forceinline__ float dec8_sw(unsigned int b) {
    return __half2float(__ushort_as_half((unsigned short)(b << 8)));
}
#endif

__device__ __forceinline__ unsigned int enc4(float a, float b, float c, float d) {
#ifdef HWFP8
    int r = __builtin_amdgcn_cvt_pk_fp8_f32(a, b, 0, false);
    r = __builtin_amdgcn_cvt_pk_fp8_f32(c, d, r, true);
    return (unsigned int)r;
#else
    return enc8_sw(a) | (enc8_sw(b) << 8) | (enc8_sw(c) << 16) | (enc8_sw(d) << 24);
#endif
}

__device__ __forceinline__ void dec4(unsigned int w, float* f) {
#ifdef HWFP8
    vfloat2 a = __builtin_amdgcn_cvt_pk_f32_fp8((int)w, false);
    vfloat2 b = __builtin_amdgcn_cvt_pk_f32_fp8((int)w, true);
    f[0] = a.x; f[1] = a.y; f[2] = b.x; f[3] = b.y;
#else
    f[0] = dec8_sw(w & 0xffu); f[1] = dec8_sw((w >> 8) & 0xffu);
    f[2] = dec8_sw((w >> 16) & 0xffu); f[3] = dec8_sw(w >> 24);
#endif
}

__device__ __forceinline__ void dec8(uint2 g, float* f) {
    dec4(g.x, f);
    dec4(g.y, f + 4);
}

// ---------------- GEMM epilogue (per-wave LDS transpose + fp8 pack) ----------------
__device__ __forceinline__ void gemm_epilogue(float* so, const f32x4* acc,
                                              unsigned int* Yq, float S,
                                              int r0w, int rowsTot, int lane) {
    int cc = lane & 15;
    int cr = (lane >> 4) * 4;
#pragma unroll
    for (int c = 0; c < 4; ++c) {
        so[(cr + 0) * 68 + c * 16 + cc] = acc[c][0];
        so[(cr + 1) * 68 + c * 16 + cc] = acc[c][1];
        so[(cr + 2) * 68 + c * 16 + cc] = acc[c][2];
        so[(cr + 3) * 68 + c * 16 + cc] = acc[c][3];
    }
    __syncthreads();
#pragma unroll
    for (int i = 0; i < 4; ++i) {
        int idx = lane + i * 64;
        int row = idx >> 4, ci = idx & 15;
        int grow = r0w + row;
        if (grow < rowsTot) {
            float4 v = *(const float4*)&so[row * 68 + ci * 4];
            Yq[(size_t)grow * 16 + ci] = enc4(v.x * S, v.y * S, v.z * S, v.w * S);
        }
    }
}

// ---------------- fused dispatch 1: GEMM1 (x fp32, W1 via LDS) || pre-count ----------------
__global__ __launch_bounds__(256) void k_fused1(const float* __restrict__ x,
                                                const float* __restrict__ W1,
                                                unsigned int* __restrict__ Yq,
                                                float S, int N, int rowsTot, int gGf,
                                                const int* __restrict__ edst, int* __restrict__ deg, int E,
                                                const int* __restrict__ pcol, int* __restrict__ ccnt, int P,
                                                const float* __restrict__ W2, const float* __restrict__ W3,
                                                unsigned short* __restrict__ Wt) {
    __shared__ float sOut[4][16 * 68];
    __shared__ unsigned short sW[4096];   // W1 bf16, [c][k]
    int tid = threadIdx.x;
    if ((int)blockIdx.x < gGf) {
        int w = tid >> 6, lane = tid & 63;
        int cc = lane & 15, kg = (lane >> 4) * 8;
        float* so = &sOut[w][0];
#pragma unroll
        for (int i = 0; i < 16; ++i) {
            int idx = i * 256 + tid;
            int k = idx >> 6, c = idx & 63;
            sW[c * 64 + k] = f2bf(W1[idx]);
        }
        __syncthreads();
        ABFrag bf[2][4];
#pragma unroll
        for (int h = 0; h < 2; ++h)
#pragma unroll
            for (int c = 0; c < 4; ++c)
                bf[h][c].s = *(const short8_t*)&sW[(c * 16 + cc) * 64 + h * 32 + kg];

        int base = blockIdx.x * 128;
        ABFrag a[2];
        auto loadA = [&](int rA, ABFrag* dst) {
#pragma unroll
            for (int h = 0; h < 2; ++h) {
                if (rA < rowsTot) {
                    int n = rA >> 3, b = rA & 7;
                    const float* p = &x[((size_t)b * N + n) * 64 + h * 32 + kg];
                    float4 v0 = *(const float4*)p;
                    float4 v1 = *(const float4*)(p + 4);
                    dst[h].u[0] = f2bf(v0.x); dst[h].u[1] = f2bf(v0.y);
                    dst[h].u[2] = f2bf(v0.z); dst[h].u[3] = f2bf(v0.w);
                    dst[h].u[4] = f2bf(v1.x); dst[h].u[5] = f2bf(v1.y);
                    dst[h].u[6] = f2bf(v1.z); dst[h].u[7] = f2bf(v1.w);
                } else {
#pragma unroll
                    for (int j = 0; j < 8; ++j) dst[h].u[j] = 0;
                }
            }
        };
        loadA(base + w * 16 + (lane & 15), a);
#pragma unroll
        for (int t = 0; t < 2; ++t) {
            ABFrag an[2];
            if (t < 1) loadA(base + 64 + w * 16 + (lane & 15), an);
            f32x4 acc[4] = {f32x4{}, f32x4{}, f32x4{}, f32x4{}};
#pragma unroll
            for (int h = 0; h < 2; ++h)
#pragma unroll
                for (int c = 0; c < 4; ++c)
                    acc[c] = __builtin_amdgcn_mfma_f32_16x16x32_bf16(a[h].s, bf[h][c].s, acc[c], 0, 0, 0);
            gemm_epilogue(so, acc, Yq, S, base + t * 64 + w * 16, rowsTot, lane);
            if (t < 1) { a[0] = an[0]; a[1] = an[1]; __syncthreads(); }
        }
    } else {
        int cb = blockIdx.x - gGf;
        int nCB = gridDim.x - gGf;
        int gth = cb * 256 + tid;
        int GT = nCB * 256;
        for (int e = gth; e < E; e += GT) atomicAdd(&deg[edst[e]], 1);
        for (int p = gth; p < P; p += GT) atomicAdd(&ccnt[pcol[p]], 1);
        for (int i = gth; i < 2 * 4096; i += GT) {
            int l = i >> 12, r = i & 4095;
            int k = r >> 6, c = r & 63;
            const float* W = (l == 0) ? W2 : W3;
            Wt[(l << 12) + c * 64 + k] = f2bf(W[r]);
        }
    }
}

// ---------------- remaining preprocessing (proven R2) ----------------

__global__ __launch_bounds__(256) void k_pre_scan(const int* __restrict__ deg, int* __restrict__ rowoff, int N,
                                                  const int* __restrict__ ccnt, int* __restrict__ coff, int NC,
                                                  float* __restrict__ dinv) {
    __shared__ int part[256];
    int t = threadIdx.x;
    int gth = blockIdx.x * blockDim.x + t;
    int GT = gridDim.x * blockDim.x;
    for (int i = gth; i < N; i += GT) dinv[i] = rsqrtf((float)(deg[i] + 1));

    const int* cnt = nullptr; int* off = nullptr; int n = 0;
    if (blockIdx.x == 0)      { cnt = deg;  off = rowoff; n = N; }
    else if (blockIdx.x == 1) { cnt = ccnt; off = coff;   n = NC; }
    else return;

    int CH = (n + 255) >> 8;
    int lo = min(t * CH, n), hi = min(lo + CH, n);
    int sum = 0;
    for (int i = lo; i < hi; ++i) sum += cnt[i];
    part[t] = sum;
    __syncthreads();
    for (int o = 1; o < 256; o <<= 1) {
        int v = (t >= o) ? part[t - o] : 0;
        __syncthreads();
        part[t] += v;
        __syncthreads();
    }
    int run = (t == 0) ? 0 : part[t - 1];
    for (int i = lo; i < hi; ++i) { off[i] = run; run += cnt[i]; }
    if (t == 255) off[n] = run;
}

__global__ __launch_bounds__(256) void k_pre_scatter(const int* __restrict__ esrc, const int* __restrict__ edst,
                                                     const float* __restrict__ dinv, const int* __restrict__ rowoff,
                                                     int* __restrict__ fill, int* __restrict__ ssrc,
                                                     float* __restrict__ snorm, int E,
                                                     const int* __restrict__ prow, const int* __restrict__ pcol,
                                                     const int* __restrict__ coff, int* __restrict__ cfill,
                                                     int* __restrict__ crow, int P) {
    int gth = blockIdx.x * blockDim.x + threadIdx.x;
    int GT = gridDim.x * blockDim.x;
    for (int e = gth; e < E; e += GT) {
        int s = esrc[e], d = edst[e];
        int pos = rowoff[d] + atomicAdd(&fill[d], 1);
        ssrc[pos]  = s;
        snorm[pos] = dinv[s] * dinv[d];
    }
    for (int p = gth; p < P; p += GT) {
        int c = pcol[p];
        int pos = coff[c] + atomicAdd(&cfill[c], 1);
        crow[pos] = prow[p];
    }
}

// ---------------- agg core: coalesced edge metadata + shfl broadcast (R9) ----------------
// Serial fallback path; also the deg>64 / tail-node path. Bit-identical math.
template<int LAYER>
__device__ __forceinline__ void agg_node(const uint2* __restrict__ Y,
                                         const int* __restrict__ rowoff,
                                         const int* __restrict__ ssrc,
                                         const float* __restrict__ snorm,
                                         const float* __restrict__ dinv,
                                         const float* bv, const float* wv,
                                         float* __restrict__ sArr,
                                         float invS, int n, int lane,
                                         float* accOut) {
    float dn = dinv[n];
    float w0 = dn * dn;
    int beg = rowoff[n], end = rowoff[n + 1];

    uint2 gs = Y[(size_t)n * 64 + lane];       // self row: issue first
    float acc[8] = {0.f, 0.f, 0.f, 0.f, 0.f, 0.f, 0.f, 0.f};
    float f[8];
    bool haveSelf = false;

    for (int base = beg; base < end; base += 64) {
        int e = base + lane;
        int myIdx = (e < end) ? ssrc[e] : 0;       // coalesced: 64 edges/load
        float myW  = (e < end) ? snorm[e] : 0.f;
        int cnt = min(end - base, 64);
        for (int i = 0; i < cnt; i += 8) {
            int   sI[8];
            float wI[8];
            uint2 g[8];
#pragma unroll
            for (int u = 0; u < 8; ++u) {
                sI[u] = __shfl(myIdx, i + u, 64);   // register broadcast
                wI[u] = __shfl(myW,  i + u, 64);    // pad lanes carry w=0
            }
#pragma unroll
            for (int u = 0; u < 8; ++u) g[u] = Y[(size_t)sI[u] * 64 + lane];
            if (!haveSelf) {                        // consume self under batch-0 latency
                dec8(gs, f);
#pragma unroll
                for (int k = 0; k < 8; ++k) acc[k] = w0 * f[k];
                haveSelf = true;
            }
#pragma unroll
            for (int u = 0; u < 8; ++u) {
                dec8(g[u], f);
#pragma unroll
                for (int k = 0; k < 8; ++k) acc[k] = fmaf(wI[u], f[k], acc[k]);
            }
        }
    }
    if (!haveSelf) {                            // deg == 0
        dec8(gs, f);
#pragma unroll
        for (int k = 0; k < 8; ++k) acc[k] = w0 * f[k];
    }

    float sv = 0.f;
#pragma unroll
    for (int k = 0; k < 8; ++k) {
        float o = fmaxf(fmaf(acc[k], invS, bv[k]), 0.f);
        accOut[k] = o;
        sv = fmaf(o, wv[k], sv);
    }
    sv += __shfl_down(sv, 4, 64);
    sv += __shfl_down(sv, 2, 64);
    sv += __shfl_down(sv, 1, 64);
    if ((lane & 7) == 0) {
        int b = lane >> 3;
        float* sp = sArr + (size_t)n * 8 + b;
        if (LAYER == 0) *sp = sv;
        else            *sp += sv;
    }
}

// ---------------- dual-node interleaved agg: 16 gathers in flight per wave ----------------
// Requires: both nodes valid, deg<=64 each (single metadata chunk). Batches of
// the two nodes are interleaved (issue 8+8, consume 8+8) -> 2x memory-level
// parallelism vs serial agg_node x2. Per-node arithmetic sequence identical:
// self consumed under batch-0 latency, batch-of-8 order, zero-weight padding.
template<int LAYER>
__device__ __forceinline__ void agg_dual(const uint2* __restrict__ Y,
                                         int beg0, int end0, int beg1, int end1,
                                         const int* __restrict__ ssrc,
                                         const float* __restrict__ snorm,
                                         const float* __restrict__ dinv,
                                         const float* bv, const float* wv,
                                         float* __restrict__ sArr,
                                         float invS, int n0, int n1, int lane,
                                         float* acc0, float* acc1) {
    float dn0 = dinv[n0], w00 = dn0 * dn0;
    float dn1 = dinv[n1], w01 = dn1 * dn1;
    uint2 gs0 = Y[(size_t)n0 * 64 + lane];
    uint2 gs1 = Y[(size_t)n1 * 64 + lane];
    int e0 = beg0 + lane, e1 = beg1 + lane;
    int   mI0 = (e0 < end0) ? ssrc[e0] : 0;
    float mW0 = (e0 < end0) ? snorm[e0] : 0.f;
    int   mI1 = (e1 < end1) ? ssrc[e1] : 0;
    float mW1 = (e1 < end1) ? snorm[e1] : 0.f;
    int nb0 = (end0 - beg0 + 7) >> 3;
    int nb1 = (end1 - beg1 + 7) >> 3;
    int nbM = max(nb0, nb1);
    float f[8];

    if (nbM == 0) {                 // both deg==0
        dec8(gs0, f);
#pragma unroll
        for (int k = 0; k < 8; ++k) acc0[k] = w00 * f[k];
        dec8(gs1, f);
#pragma unroll
        for (int k = 0; k < 8; ++k) acc1[k] = w01 * f[k];
    }
    for (int i = 0; i < nbM; ++i) {
        bool h0 = i < nb0, h1 = i < nb1;       // wave-uniform
        uint2 g0[8], g1[8];
        float wI0[8], wI1[8];
        if (h0) {
            int sI0[8];
#pragma unroll
            for (int u = 0; u < 8; ++u) {
                sI0[u] = __shfl(mI0, i * 8 + u, 64);
                wI0[u] = __shfl(mW0, i * 8 + u, 64);
            }
#pragma unroll
            for (int u = 0; u < 8; ++u) g0[u] = Y[(size_t)sI0[u] * 64 + lane];
        }
        if (h1) {
            int sI1[8];
#pragma unroll
            for (int u = 0; u < 8; ++u) {
                sI1[u] = __shfl(mI1, i * 8 + u, 64);
                wI1[u] = __shfl(mW1, i * 8 + u, 64);
            }
#pragma unroll
            for (int u = 0; u < 8; ++u) g1[u] = Y[(size_t)sI1[u] * 64 + lane];
        }
        if (i == 0) {                          // consume selves under batch-0 latency
            dec8(gs0, f);
#pragma unroll
            for (int k = 0; k < 8; ++k) acc0[k] = w00 * f[k];
            dec8(gs1, f);
#pragma unroll
            for (int k = 0; k < 8; ++k) acc1[k] = w01 * f[k];
        }
        if (h0) {
#pragma unroll
            for (int u = 0; u < 8; ++u) {
                dec8(g0[u], f);
#pragma unroll
                for (int k = 0; k < 8; ++k) acc0[k] = fmaf(wI0[u], f[k], acc0[k]);
            }
        }
        if (h1) {
#pragma unroll
            for (int u = 0; u < 8; ++u) {
                dec8(g1[u], f);
#pragma unroll
                for (int k = 0; k < 8; ++k) acc1[k] = fmaf(wI1[u], f[k], acc1[k]);
            }
        }
    }

    // epilogue per node (identical to agg_node)
#pragma unroll
    for (int j = 0; j < 2; ++j) {
        float* acc = j ? acc1 : acc0;
        int n = j ? n1 : n0;
        float sv = 0.f;
#pragma unroll
        for (int k = 0; k < 8; ++k) {
            float o = fmaxf(fmaf(acc[k], invS, bv[k]), 0.f);
            acc[k] = o;
            sv = fmaf(o, wv[k], sv);
        }
        sv += __shfl_down(sv, 4, 64);
        sv += __shfl_down(sv, 2, 64);
        sv += __shfl_down(sv, 1, 64);
        if ((lane & 7) == 0) {
            int b = lane >> 3;
            float* sp = sArr + (size_t)n * 8 + b;
            if (LAYER == 0) *sp = sv;
            else            *sp += sv;
        }
    }
}

// ---------------- fused agg(L) + gemm(L+1): 8 nodes = 64 rows per block ----------------
template<int LAYER>
__global__ __launch_bounds__(256) void k_aggemm(const uint2* __restrict__ Yin,
                                                const int* __restrict__ rowoff,
                                                const int* __restrict__ ssrc,
                                                const float* __restrict__ snorm,
                                                const float* __restrict__ dinv,
                                                const float* __restrict__ bias,
                                                const float* __restrict__ fcW,
                                                float* __restrict__ sArr, float invS,
                                                const unsigned short* __restrict__ Wt,
                                                unsigned int* __restrict__ Yout, float Sout,
                                                int N, int rowsTot) {
    struct ShU { union { unsigned short sX[64 * 64]; float sOut[4][16 * 68]; }; };
    __shared__ ShU sh;
    int tid = threadIdx.x;
    int w = tid >> 6, lane = tid & 63;
    int b = lane >> 3, hb = (lane & 7) * 8;

    float bv[8], wv[8];
#pragma unroll
    for (int k = 0; k < 8; ++k) { bv[k] = bias[hb + k]; wv[k] = fcW[3 * (hb + k) + LAYER]; }

    int ln0 = w * 2;
    int n0 = blockIdx.x * 8 + ln0;
    int n1 = n0 + 1;
    bool v0 = n0 < N, v1 = n1 < N;
    int beg0 = 0, end0 = 0, beg1 = 0, end1 = 0;
    if (v0) { beg0 = rowoff[n0]; end0 = rowoff[n0 + 1]; }
    if (v1) { beg1 = rowoff[n1]; end1 = rowoff[n1 + 1]; }

    auto writeRow = [&](int j, const float* acc, bool valid) {
        int r = (ln0 + j) * 8 + b;
        unsigned int byte = (unsigned int)(r * 128 + hb * 2) ^ ((unsigned int)(r & 7) << 4);
        ABFrag xr;
        if (valid) {
#pragma unroll
            for (int k = 0; k < 8; ++k) xr.u[k] = f2bf(acc[k]);
        } else {
#pragma unroll
            for (int k = 0; k < 8; ++k) xr.u[k] = 0;
        }
        *(short8_t*)((char*)sh.sX + byte) = xr.s;
    };

    if (v0 && v1 && (end0 - beg0) <= 64 && (end1 - beg1) <= 64) {
        float acc0[8], acc1[8];
        agg_dual<LAYER>(Yin, beg0, end0, beg1, end1, ssrc, snorm, dinv, bv, wv,
                        sArr, invS, n0, n1, lane, acc0, acc1);
        writeRow(0, acc0, true);
        writeRow(1, acc1, true);
    } else {
#pragma unroll
        for (int j = 0; j < 2; ++j) {
            int n = n0 + j;
            if (n < N) {
                float acc[8];
                agg_node<LAYER>(Yin, rowoff, ssrc, snorm, dinv, bv, wv, sArr, invS, n, lane, acc);
                writeRow(j, acc, true);
            } else {
                writeRow(j, nullptr, false);
            }
        }
    }
    __syncthreads();

    // ---- GEMM on the block's 64 rows from LDS ----
    int cc = lane & 15, kg = (lane >> 4) * 8;
    ABFrag bf[2][4];
#pragma unroll
    for (int h = 0; h < 2; ++h)
#pragma unroll
        for (int c = 0; c < 4; ++c)
            bf[h][c].s = *(const short8_t*)&Wt[(size_t)(c * 16 + cc) * 64 + h * 32 + kg];

    int rA = w * 16 + (lane & 15);
    ABFrag a[2];
#pragma unroll
    for (int h = 0; h < 2; ++h) {
        unsigned int byte = (unsigned int)(rA * 128 + (h * 32 + kg) * 2) ^ ((unsigned int)(rA & 7) << 4);
        a[h].s = *(const short8_t*)((const char*)sh.sX + byte);
    }
    f32x4 acc4[4] = {f32x4{}, f32x4{}, f32x4{}, f32x4{}};
#pragma unroll
    for (int h = 0; h < 2; ++h)
#pragma unroll
        for (int c = 0; c < 4; ++c)
            acc4[c] = __builtin_amdgcn_mfma_f32_16x16x32_bf16(a[h].s, bf[h][c].s, acc4[c], 0, 0, 0);
    __syncthreads();   // all sX reads done before sOut (aliased) is written
    gemm_epilogue(&sh.sOut[w][0], acc4, Yout, Sout, blockIdx.x * 64 + w * 16, rowsTot, lane);
}

// ---------------- layer-3 aggregation (no following GEMM): dual-node per wave ----------------

template<int LAYER>
__global__ __launch_bounds__(256) void k_agg(const uint2* __restrict__ Y,
                                             const int* __restrict__ rowoff,
                                             const int* __restrict__ ssrc,
                                             const float* __restrict__ snorm,
                                             const float* __restrict__ dinv,
                                             const float* __restrict__ bias,
                                             const float* __restrict__ fcW,
                                             float* __restrict__ sArr,
                                             float invS, int N) {
    int lane = threadIdx.x & 63;
    int hb = (lane & 7) * 8;
    float bv[8], wv[8];
#pragma unroll
    for (int k = 0; k < 8; ++k) { bv[k] = bias[hb + k]; wv[k] = fcW[3 * (hb + k) + LAYER]; }

    int n0 = blockIdx.x * 8 + (threadIdx.x >> 6) * 2;
    int n1 = n0 + 1;
    bool v0 = n0 < N, v1 = n1 < N;
    if (!v0) return;
    int beg0 = rowoff[n0], end0 = rowoff[n0 + 1];
    int beg1 = 0, end1 = 0;
    if (v1) { beg1 = rowoff[n1]; end1 = rowoff[n1 + 1]; }

    if (v1 && (end0 - beg0) <= 64 && (end1 - beg1) <= 64) {
        float acc0[8], acc1[8];
        agg_dual<LAYER>(Y, beg0, end0, beg1, end1, ssrc, snorm, dinv, bv, wv,
                        sArr, invS, n0, n1, lane, acc0, acc1);
    } else {
        float acc[8];
        agg_node<LAYER>(Y, rowoff, ssrc, snorm, dinv, bv, wv, sArr, invS, n0, lane, acc);
        if (v1) agg_node<LAYER>(Y, rowoff, ssrc, snorm, dinv, bv, wv, sArr, invS, n1, lane, acc);
    }
}

// ---------------- pooling head (proven R2: one wave per column, 32 gathers in flight) ----------------

__global__ __launch_bounds__(64) void k_poolg(const float* __restrict__ sArr,
                                              const int* __restrict__ coff,
                                              const int* __restrict__ crow,
                                              float* __restrict__ hpoolT) {
    int c = blockIdx.x;
    int lane = threadIdx.x;
    int beg = coff[c], end = coff[c + 1];
    int b = lane & 7;
    float acc = 0.f;
    int i = beg + (lane >> 3);
    for (; i + 24 < end; i += 32) {
        int r0 = crow[i], r1 = crow[i + 8], r2 = crow[i + 16], r3 = crow[i + 24];
        float a0 = sArr[(size_t)r0 * 8 + b];
        float a1 = sArr[(size_t)r1 * 8 + b];
        float a2 = sArr[(size_t)r2 * 8 + b];
        float a3 = sArr[(size_t)r3 * 8 + b];
        acc += (a0 + a1) + (a2 + a3);
    }
    for (; i < end; i += 8) acc += sArr[(size_t)crow[i] * 8 + b];
    acc += __shfl_down(acc, 32, 64);
    acc += __shfl_down(acc, 16, 64);
    acc += __shfl_down(acc, 8, 64);
    if (lane < 8) {
        float inv = 1.f / fmaxf((float)(end - beg), 1.f);
        hpoolT[(size_t)c * 8 + b] = acc * inv;
    }
}

// ---------------- l1 partial + last-done head (proven R2) ----------------

__global__ __launch_bounds__(128) void k_l1f(const float* __restrict__ hpoolT,
                                             const float* __restrict__ fcb,
                                             const float* __restrict__ l1W,
                                             float* __restrict__ hpre,
                                             int* __restrict__ done,
                                             const float* __restrict__ l1b,
                                             const float* __restrict__ l2W,
                                             const float* __restrict__ l2b,
                                             float* __restrict__ out,
                                             int NC, int HFC, int bs, int NCLS,
                                             int CHUNK, int nBlocks) {
    __shared__ float hl[64];
    int b = blockIdx.y;
    int c0 = blockIdx.x * CHUNK;
    int j = threadIdx.x;
    int cend = min(c0 + CHUNK, NC);
    for (int c = c0 + j; c < cend; c += blockDim.x)
        hl[c - c0] = hpoolT[(size_t)c * 8 + b] + fcb[0];
    __syncthreads();
    float acc = 0.f;
    for (int c = c0; c < cend; ++c) acc = fmaf(hl[c - c0], l1W[(size_t)c * HFC + j], acc);
    atomicAdd(&hpre[(size_t)b * HFC + j], acc);

    __threadfence();
    __syncthreads();
    __shared__ int amLast;
    if (j == 0) amLast = (atomicAdd(done, 1) == nBlocks - 1);
    __syncthreads();
    if (!amLast) return;
    __threadfence();

    __shared__ float sZ[64];
    int g = j >> 3, l8 = j & 7;
    int nout = bs * NCLS;
    float v = 0.f;
    int b2 = g / NCLS, k2 = g - b2 * NCLS;
    if (g < nout) {
        for (int jj = l8; jj < HFC; jj += 8) {
            float h = fmaxf(hpre[(size_t)b2 * HFC + jj] + l1b[jj], 0.f);
            v = fmaf(h, l2W[(size_t)jj * NCLS + k2], v);
        }
    }
    v += __shfl_down(v, 4, 8);
    v += __shfl_down(v, 2, 8);
    v += __shfl_down(v, 1, 8);
    if (l8 == 0 && g < nout) sZ[g] = v + l2b[k2];
    __syncthreads();
    if (j < bs) {
        float m = -1e30f;
        for (int c = 0; c < NCLS; ++c) m = fmaxf(m, sZ[j * NCLS + c]);
        float s = 0.f;
        for (int c = 0; c < NCLS; ++c) s += expf(sZ[j * NCLS + c] - m);
        float lse = m + logf(s);
        for (int c = 0; c < NCLS; ++c) out[j * NCLS + c] = sZ[j * NCLS + c] - lse;
    }
}

// ---------------- launcher ----------------

extern "C" void kernel_launch(void* const* d_in, const int* in_sizes, int n_in,
                              void* d_out, int out_size, void* d_ws, size_t ws_size,
                              hipStream_t stream) {
    const float* x   = (const float*)d_in[0];
    const int* eidx  = (const int*)d_in[2];
    const int* prow  = (const int*)d_in[3];
    const int* pcol  = (const int*)d_in[4];
    const float* W1  = (const float*)d_in[5];
    const float* b1  = (const float*)d_in[6];
    const float* W2  = (const float*)d_in[7];
    const float* b2  = (const float*)d_in[8];
    const float* W3  = (const float*)d_in[9];
    const float* b3  = (const float*)d_in[10];
    const float* fcW = (const float*)d_in[11];
    const float* fcb = (const float*)d_in[12];
    const float* l1W = (const float*)d_in[13];
    const float* l1b = (const float*)d_in[14];
    const float* l2W = (const float*)d_in[15];
    const float* l2b = (const float*)d_in[16];
    float* out = (float*)d_out;

    const int bs   = in_sizes[1];                 // 8
    const int E    = in_sizes[2] / 2;
    const int P    = in_sizes[3];
    const int N    = in_sizes[0] / (bs * HID);
    const int HFC  = in_sizes[14];                // 128
    const int NC   = in_sizes[13] / HFC;          // 1000
    const int NCLS = in_sizes[15] / HFC;          // 2
    const int rows = N * bs;

    const int* esrc = eidx;
    const int* edst = eidx + E;

    size_t off = 0;
    auto alloc = [&](size_t bytes) -> void* {
        void* r = (char*)d_ws + off;
        off += (bytes + 255) & ~(size_t)255;
        return r;
    };
    // ---- zero region (one memset) ----
    char* zbase   = (char*)d_ws;
    int*   deg    = (int*)  alloc((size_t)N * 4);
    int*   fill   = (int*)  alloc((size_t)N * 4);
    int*   ccnt   = (int*)  alloc((size_t)NC * 4);
    int*   cfill  = (int*)  alloc((size_t)NC * 4);
    float* hpre   = (float*)alloc((size_t)bs * HFC * 4);
    int*   done   = (int*)  alloc(4);
    size_t zspan  = off;
    // ---- rest ----
    float* dinv   = (float*)alloc((size_t)N * 4);
    int*   rowoff = (int*)  alloc(((size_t)N + 1) * 4);
    int*   coff   = (int*)  alloc(((size_t)NC + 1) * 4);
    int*   crow   = (int*)  alloc((size_t)P * 4);
    float* hpoolT = (float*)alloc((size_t)NC * bs * 4);
    int*   ssrc   = (int*)  alloc((size_t)E * 4);
    float* snorm  = (float*)alloc((size_t)E * 4);
    unsigned int* Yqa  = (unsigned int*)alloc((size_t)rows * HID);
    unsigned int* Yqb  = (unsigned int*)alloc((size_t)rows * HID);
    float* sArr   = (float*)alloc((size_t)rows * 4);
    unsigned short* Wt = (unsigned short*)alloc((size_t)2 * 64 * 64 * 2);

    hipMemsetAsync(zbase, 0, zspan, stream);

    const float S1 = 1.f,  iS1 = 1.f;
    const float S2 = 16.f, iS2 = 1.f / 16.f;
    const float S3 = 128.f, iS3 = 1.f / 128.f;

    int gG2 = (rows + 127) / 128;   // 946
    int gF  = (N + 7) / 8;          // 1892 (aggemm blocks: 8 nodes = 64 rows)
    int gPre = 512;

    // dispatch 1: GEMM1 (x, W1-via-LDS) || degree/col counts + Wt(W2,W3)
    k_fused1<<<gG2 + gPre, 256, 0, stream>>>(x, W1, Yqa, S1, N, rows, gG2,
                                             edst, deg, E, pcol, ccnt, P, W2, W3, Wt);
    k_pre_scan<<<64, 256, 0, stream>>>(deg, rowoff, N, ccnt, coff, NC, dinv);
    k_pre_scatter<<<gPre, 256, 0, stream>>>(esrc, edst, dinv, rowoff, fill, ssrc, snorm, E,
                                            prow, pcol, coff, cfill, crow, P);

    // fused agg1+gemm2 (Yqa -> Yqb), agg2+gemm3 (Yqb -> Yqa), agg3
    k_aggemm<0><<<gF, 256, 0, stream>>>((const uint2*)Yqa, rowoff, ssrc, snorm, dinv, b1, fcW,
                                        sArr, iS1, Wt, Yqb, S2, N, rows);
    k_aggemm<1><<<gF, 256, 0, stream>>>((const uint2*)Yqb, rowoff, ssrc, snorm, dinv, b2, fcW,
                                        sArr, iS2, Wt + 4096, Yqa, S3, N, rows);
    k_agg<2><<<gF, 256, 0, stream>>>((const uint2*)Yqa, rowoff, ssrc, snorm, dinv, b3, fcW,
                                     sArr, iS3, N);

    k_poolg<<<NC, 64, 0, stream>>>(sArr, coff, crow, hpoolT);

    const int CHUNK = 40;
    dim3 gL1((NC + CHUNK - 1) / CHUNK, bs);
    int nBlocks = gL1.x * gL1.y;   // 200
    k_l1f<<<gL1, 128, 0, stream>>>(hpoolT, fcb, l1W, hpre, done, l1b, l2W, l2b, out,
                                   NC, HFC, bs, NCLS, CHUNK, nBlocks);
}